// Round 1
// baseline (455.303 us; speedup 1.0000x reference)
//
#include <hip/hip_runtime.h>

#define DIM 144
#define ROWS 64
#define LSTRIDE 65            // 64 rows padded to 65 -> all LDS phases conflict-free
#define TILE_ELEMS (ROWS * DIM)   // 9216 floats per tile
#define LOADS_PER_THREAD (TILE_ELEMS / 256)  // 36

// ---------------------------------------------------------------------------
// Kernel 1: build Cw[9][16][16] — per-(l,t)-unit 16x16 mixing matrices.
// C[p][v][u] = mixing[k, i0, j0] * norm[i0, j0] * weight[k]
// with k = l*256 + v*16 + u (reference path ordering: n-major, then v, then u),
// i0 = off_l + v*d + t, j0 = off_l + u*d + t.  Reads actual mixing/norm values
// so the CG (1/sqrt(2l+1)) and norm (1/4) constants are taken from the inputs.
// ---------------------------------------------------------------------------
__global__ __launch_bounds__(256) void build_C(
    const float* __restrict__ weight,
    const float* __restrict__ mixing,
    const float* __restrict__ norm,
    float* __restrict__ Cw)
{
    int idx = blockIdx.x * 256 + threadIdx.x;   // 0 .. 2303
    if (idx >= 9 * 256) return;
    int p  = idx >> 8;          // unit 0..8
    int vu = idx & 255;
    int v = vu >> 4, u = vu & 15;
    int l, t, off;
    if (p == 0)      { l = 0; t = 0;     off = 0;  }
    else if (p < 4)  { l = 1; t = p - 1; off = 16; }
    else             { l = 2; t = p - 4; off = 64; }
    int d  = 2 * l + 1;
    int k  = l * 256 + v * 16 + u;
    int i0 = off + v * d + t;
    int j0 = off + u * d + t;
    float m  = mixing[(size_t)k * (DIM * DIM) + i0 * DIM + j0];
    float nc = norm[i0 * DIM + j0];
    Cw[idx] = m * nc * weight[k];
}

// ---------------------------------------------------------------------------
// Kernel 2: streaming kernel. 64-row tile per block, 256 threads (4 waves).
// LDS layout: buf[col * 65 + row]  (col-major, padded) =>
//   stage-in  (lane stride 65)          : banks step 1  -> conflict-free
//   unit reads/writes (lane stride 1)   : 2-way         -> free
//   stage-out (lane stride 65)          : conflict-free
// Wave w owns units {w, w+4, w+8} — columns disjoint across waves, each lane
// only touches its own row => no barriers inside the compute phase.
// C accessed with wave-uniform addresses -> s_load through constant cache.
// ---------------------------------------------------------------------------
__global__ __launch_bounds__(256) void tp_linear_kernel(
    const float* __restrict__ feat,
    const float* __restrict__ Cw,
    float* __restrict__ out,
    long long total_elems)
{
    __shared__ float buf[DIM * LSTRIDE];
    const int tid = threadIdx.x;
    const long long tileBase = (long long)blockIdx.x * TILE_ELEMS;

    // ---- stage in (coalesced dword loads, conflict-free LDS writes) ----
#pragma unroll
    for (int it = 0; it < LOADS_PER_THREAD; ++it) {
        int e   = it * 256 + tid;            // 0 .. 9215
        int row = e / DIM;
        int col = e - row * DIM;
        long long g = tileBase + e;
        float v = (g < total_elems) ? feat[g] : 0.0f;
        buf[col * LSTRIDE + row] = v;
    }
    __syncthreads();

    const int r = tid & 63;    // lane = row within tile
    const int w = tid >> 6;    // wave id 0..3

    for (int p = w; p < 9; p += 4) {
        int l, t, off;
        if (p == 0)      { l = 0; t = 0;     off = 0;  }
        else if (p < 4)  { l = 1; t = p - 1; off = 16; }
        else             { l = 2; t = p - 4; off = 64; }
        int d = 2 * l + 1;
        const float* __restrict__ C = Cw + p * 256;

        float fin[16];
#pragma unroll
        for (int u = 0; u < 16; ++u)
            fin[u] = buf[(off + u * d + t) * LSTRIDE + r];

        float acc[16];
#pragma unroll
        for (int v = 0; v < 16; ++v) {
            float a = 0.0f;
#pragma unroll
            for (int u = 0; u < 16; ++u)
                a += C[v * 16 + u] * fin[u];
            acc[v] = a;
        }
#pragma unroll
        for (int v = 0; v < 16; ++v)
            buf[(off + v * d + t) * LSTRIDE + r] = acc[v];
    }
    __syncthreads();

    // ---- stage out (conflict-free LDS reads, coalesced dword stores) ----
#pragma unroll
    for (int it = 0; it < LOADS_PER_THREAD; ++it) {
        int e   = it * 256 + tid;
        int row = e / DIM;
        int col = e - row * DIM;
        long long g = tileBase + e;
        if (g < total_elems)
            out[g] = buf[col * LSTRIDE + row];
    }
}

extern "C" void kernel_launch(void* const* d_in, const int* in_sizes, int n_in,
                              void* d_out, int out_size, void* d_ws, size_t ws_size,
                              hipStream_t stream)
{
    const float* feat   = (const float*)d_in[0];   // [B, 144]
    const float* weight = (const float*)d_in[1];   // [768]
    const float* mixing = (const float*)d_in[2];   // [768, 144, 144]
    const float* norm   = (const float*)d_in[3];   // [144, 144]
    float* out = (float*)d_out;
    float* Cw  = (float*)d_ws;                     // 9*256 floats = 9216 B

    long long total = (long long)in_sizes[0];      // B * 144
    int nrows = (int)(total / DIM);
    int tiles = (nrows + ROWS - 1) / ROWS;

    build_C<<<9, 256, 0, stream>>>(weight, mixing, norm, Cw);
    tp_linear_kernel<<<tiles, 256, 0, stream>>>(feat, Cw, out, total);
}

// Round 2
// 334.244 us; speedup vs baseline: 1.3622x; 1.3622x over previous
//
#include <hip/hip_runtime.h>

#define DIM 144
#define ROWS 64
#define TILE_ELEMS (ROWS * DIM)        // 9216 floats per tile
#define TILE_F4 (TILE_ELEMS / 4)       // 2304 float4 per tile
#define F4_PER_THREAD (TILE_F4 / 256)  // 9

// ---------------------------------------------------------------------------
// Kernel 1: build Cw[9][16][16] — per-(l,t)-unit 16x16 mixing matrices.
// C[p][v][u] = mixing[k, i0, j0] * norm[i0, j0] * weight[k]
// k = l*256 + v*16 + u (reference path order), i0 = off+v*d+t, j0 = off+u*d+t.
// ---------------------------------------------------------------------------
__global__ __launch_bounds__(256) void build_C(
    const float* __restrict__ weight,
    const float* __restrict__ mixing,
    const float* __restrict__ norm,
    float* __restrict__ Cw)
{
    int idx = blockIdx.x * 256 + threadIdx.x;   // 0 .. 2303
    if (idx >= 9 * 256) return;
    int p  = idx >> 8;          // unit 0..8
    int vu = idx & 255;
    int v = vu >> 4, u = vu & 15;
    int l, t, off;
    if (p == 0)      { l = 0; t = 0;     off = 0;  }
    else if (p < 4)  { l = 1; t = p - 1; off = 16; }
    else             { l = 2; t = p - 4; off = 64; }
    int d  = 2 * l + 1;
    int k  = l * 256 + v * 16 + u;
    int i0 = off + v * d + t;
    int j0 = off + u * d + t;
    float m  = mixing[(size_t)k * (DIM * DIM) + i0 * DIM + j0];
    float nc = norm[i0 * DIM + j0];
    Cw[idx] = m * nc * weight[k];
}

// ---------------------------------------------------------------------------
// Kernel 2: streaming transpose-mix-transpose. 64-row tile, 256 threads.
// LDS layout (XOR swizzle, no padding, 36 KB):
//   addr(col,row) = col*64 + (row ^ (col>>2))
//   bank = (row ^ (col>>2)) % 32
//   - compute phase (fixed col, lane=row): XOR bijection over lanes -> 2/bank, free
//   - stage phases (fixed row-ish, col varies): (col>>2) spans ~36 consecutive
//     values -> banks near-uniform, <=3-way typical
// Global I/O is float4 (16 B/lane), 9 loads + 9 stores per thread, all loads
// issued before any LDS write -> deep MLP.
// ---------------------------------------------------------------------------
__device__ __forceinline__ void unit_params(int p, int& d, int& t, int& off) {
    int l;
    if (p == 0)      { l = 0; t = 0;     off = 0;  }
    else if (p < 4)  { l = 1; t = p - 1; off = 16; }
    else             { l = 2; t = p - 4; off = 64; }
    d = 2 * l + 1;
}

__global__ __launch_bounds__(256) void tp_linear_kernel(
    const float4* __restrict__ feat4,
    const float* __restrict__ Cw,
    float4* __restrict__ out4,
    long long total4)
{
    __shared__ float buf[DIM * 64];
    const int tid = threadIdx.x;
    const long long base4 = (long long)blockIdx.x * TILE_F4;
    const bool full = (base4 + TILE_F4 <= total4);

    // ---- stage in: 9 coalesced float4 loads, then swizzled b32 LDS writes ----
    float4 v[F4_PER_THREAD];
    if (full) {
#pragma unroll
        for (int i = 0; i < F4_PER_THREAD; ++i)
            v[i] = feat4[base4 + i * 256 + tid];
    } else {
#pragma unroll
        for (int i = 0; i < F4_PER_THREAD; ++i) {
            long long g = base4 + i * 256 + tid;
            v[i] = (g < total4) ? feat4[g] : make_float4(0.f, 0.f, 0.f, 0.f);
        }
    }
#pragma unroll
    for (int i = 0; i < F4_PER_THREAD; ++i) {
        int e4  = i * 256 + tid;       // float4 index within tile
        int row = e4 / 36;
        int c   = e4 - row * 36;       // float4-column 0..35
        float* p = &buf[(4 * c) * 64 + (row ^ c)];   // swz(4c+j) = c for j=0..3
        p[0]       = v[i].x;
        p[64]      = v[i].y;
        p[128]     = v[i].z;
        p[192]     = v[i].w;
    }
    __syncthreads();

    // ---- compute: wave w owns units {w, w+4, w+8}; lane = row ----
    const int r = tid & 63;
    const int w = tid >> 6;
    for (int p = w; p < 9; p += 4) {
        int d, t, off;
        unit_params(p, d, t, off);
        const float* __restrict__ C = Cw + p * 256;   // wave-uniform -> s_load

        float fin[16];
#pragma unroll
        for (int u = 0; u < 16; ++u) {
            int col = off + u * d + t;
            fin[u] = buf[col * 64 + (r ^ (col >> 2))];
        }
        float acc[16];
#pragma unroll
        for (int vv = 0; vv < 16; ++vv) {
            float a = 0.0f;
#pragma unroll
            for (int u = 0; u < 16; ++u)
                a += C[vv * 16 + u] * fin[u];
            acc[vv] = a;
        }
#pragma unroll
        for (int vv = 0; vv < 16; ++vv) {
            int col = off + vv * d + t;
            buf[col * 64 + (r ^ (col >> 2))] = acc[vv];
        }
    }
    __syncthreads();

    // ---- stage out: swizzled b32 LDS reads, 9 coalesced float4 stores ----
#pragma unroll
    for (int i = 0; i < F4_PER_THREAD; ++i) {
        int e4  = i * 256 + tid;
        int row = e4 / 36;
        int c   = e4 - row * 36;
        const float* p = &buf[(4 * c) * 64 + (row ^ c)];
        float4 o = make_float4(p[0], p[64], p[128], p[192]);
        if (full) {
            out4[base4 + e4] = o;
        } else {
            long long g = base4 + e4;
            if (g < total4) out4[g] = o;
        }
    }
}

extern "C" void kernel_launch(void* const* d_in, const int* in_sizes, int n_in,
                              void* d_out, int out_size, void* d_ws, size_t ws_size,
                              hipStream_t stream)
{
    const float* feat   = (const float*)d_in[0];   // [B, 144]
    const float* weight = (const float*)d_in[1];   // [768]
    const float* mixing = (const float*)d_in[2];   // [768, 144, 144]
    const float* norm   = (const float*)d_in[3];   // [144, 144]
    float* out = (float*)d_out;
    float* Cw  = (float*)d_ws;                     // 9*256 floats

    long long total  = (long long)in_sizes[0];     // B * 144
    long long total4 = total / 4;                  // 144 % 4 == 0
    int nrows = (int)(total / DIM);
    int tiles = (nrows + ROWS - 1) / ROWS;

    build_C<<<9, 256, 0, stream>>>(weight, mixing, norm, Cw);
    tp_linear_kernel<<<tiles, 256, 0, stream>>>(
        (const float4*)feat, Cw, (float4*)out, total4);
}